// Round 12
// baseline (349.393 us; speedup 1.0000x reference)
//
#include <hip/hip_runtime.h>
#include <hip/hip_bf16.h>
#include <stdint.h>

// Problem dims: B=4, S=2048 -> M=8192; IN=K=4096; OUT=N=4096; R=16
#define M_DIM 8192
#define N_DIM 4096
#define K_DIM 4096
#define R_DIM 16
#define NT    (K_DIM / 64)   // 64 K-tiles of BK=64

typedef __bf16 bf16x8 __attribute__((ext_vector_type(8)));
typedef float f32x16 __attribute__((ext_vector_type(16)));
typedef unsigned short u16x8 __attribute__((ext_vector_type(8)));

#define AS1(p) ((const __attribute__((address_space(1))) void*)(p))
#define AS3(p) ((__attribute__((address_space(3))) void*)(p))

// R4/R8-style macros (empirically fastest across R3-R10 variants).
#define BAR() do { asm volatile("" ::: "memory"); __builtin_amdgcn_s_barrier(); asm volatile("" ::: "memory"); } while (0)
#define VMCNT2() asm volatile("s_waitcnt vmcnt(2)" ::: "memory")
#define VMCNT0() asm volatile("s_waitcnt vmcnt(0)" ::: "memory")
#define VMCNT8() asm volatile("s_waitcnt vmcnt(8)" ::: "memory")

__device__ __forceinline__ unsigned short f2bf(float f) {
  unsigned u = __builtin_bit_cast(unsigned, f);
  u += 0x7FFFu + ((u >> 16) & 1u);   // round-to-nearest-even
  return (unsigned short)(u >> 16);
}

// ---------------------------------------------------------------------------
// prep (R8 version, row-major awb): blocks [0,1024): awb = bf16(W*(1+A^T B^T))
//       blocks [1024,5120): xb = bf16(x)
// ---------------------------------------------------------------------------
#define CVT_BLOCKS 4096
__global__ void __launch_bounds__(256) prep_kernel(
    const float* __restrict__ x, const float* __restrict__ W,
    const float* __restrict__ lA, const float* __restrict__ lB,
    unsigned short* __restrict__ xb, unsigned short* __restrict__ awb) {
  __shared__ float Asub[16 * 512];
  __shared__ float Bsub[32 * 16];
  const int tid = threadIdx.x;

  if (blockIdx.x < 1024) {
    const int i0 = (blockIdx.x & 7) * 512;
    const int o0 = (blockIdx.x >> 3) * 32;
    for (int idx = tid; idx < 16 * 512; idx += 256) {
      int r = idx >> 9, i = idx & 511;
      Asub[idx] = lA[r * K_DIM + i0 + i];
    }
    for (int idx = tid; idx < 32 * 16; idx += 256) {
      int o = idx >> 4, r = idx & 15;
      Bsub[idx] = lB[(o0 + o) * R_DIM + r];
    }
    __syncthreads();
    for (int idx = tid; idx < 32 * 512; idx += 256) {
      int o = idx >> 9, i = idx & 511;
      float s = 1.0f;
#pragma unroll
      for (int r = 0; r < 16; ++r) s += Asub[r * 512 + i] * Bsub[o * 16 + r];
      size_t g = (size_t)(o0 + o) * K_DIM + i0 + i;
      awb[g] = f2bf(W[g] * s);
    }
  } else {
    const long total = (long)M_DIM * K_DIM;
    long i = ((long)(blockIdx.x - 1024) * 256 + tid) * 8;
    const long stride = (long)CVT_BLOCKS * 256 * 8;
    for (; i < total; i += stride) {
      const float4* p = (const float4*)(x + i);
      float4 f0 = p[0], f1 = p[1];
      u16x8 v;
      v[0] = f2bf(f0.x); v[1] = f2bf(f0.y); v[2] = f2bf(f0.z); v[3] = f2bf(f0.w);
      v[4] = f2bf(f1.x); v[5] = f2bf(f1.y); v[6] = f2bf(f1.z); v[7] = f2bf(f1.w);
      *(u16x8*)(xb + i) = v;
    }
  }
}

// ---------------------------------------------------------------------------
// GEMM: out[m,n] = sum_k xb[m,k]*awb[n,k] + bias[n]
// 256x256 tile, BK=64, 8 waves (2Mx4N), per-wave 128x64 via 32x32x16 MFMA
// (R11 structure) with the bank-conflict fix:
// LDS subtile (32 rows x 16 k = 1KB): elem (r,k) at byte
//   (k>>3)*512 + r*16 + (k&7)*2
// -> fragment ds_read of lane l (needs A[row=l&31][k=(l>>5)*8+e]) is at
//    subtile_base + l*16: 64 lanes read 1KB CONTIGUOUSLY = canonical
//    conflict-free pattern (R11's stride-64 layout was an 8-way conflict,
//    SQ_LDS_BANK_CONFLICT 2.5e7 -> predicted ~0).
// -> gll linear write (lane*16B) maps to global row = l&31, kbyte =
//    (l>>5)*16 within the 32B k-slice of issue j; the wave's 4 back-to-back
//    issues consume each 128B row-line fully (no over-fetch).
// Schedule (R8-proven ledger, unchanged):
//  PhA(t): stage B kg01(t+2) | mma kk01(t) | ds_read kk23(t) | VMCNT2 | BAR
//  PhB(t): stage B kg23 + A kg0-3 (t+2) | mma kk23(t) | ds_read kk01(t+1) | BAR
// vmcnt FIFO at PhA(t): [t+1: 8][B01(t+2): 2] -> VMCNT2 completes all of t+1.
// C/D map (m74/m101): col=lane&31, row=(reg&3)+8*(reg>>2)+4*(lane>>5).
// ---------------------------------------------------------------------------
__global__ void __launch_bounds__(512, 2) gemm_kernel(
    const unsigned short* __restrict__ Ag,   // [M][K] bf16 bits (x)
    const unsigned short* __restrict__ Bg,   // [N][K] bf16 bits (adapted W)
    const float* __restrict__ bias,
    float* __restrict__ out) {
  __shared__ __attribute__((aligned(16))) char LDSc[2 * 65536];  // 128KB

  // Bijective XCD swizzle (row-major, R8's proven locality): grid = 512.
  const int nwg = gridDim.x;
  const int q8 = nwg >> 3;
  const int wg = blockIdx.x;
  const int swz = (wg & 7) * q8 + (wg >> 3);
  const int tiles_n = N_DIM / 256;           // 16
  const int brow = (swz / tiles_n) * 256;
  const int bcol = (swz % tiles_n) * 256;

  const int tid = threadIdx.x;
  const int lane = tid & 63;
  const int w = tid >> 6;                    // wave 0..7
  const int wr = w >> 2, wc = w & 3;         // 2M x 4N wave grid

  // gll source map: lane l writes LDS chunk l of the subtile, which holds
  // global (row = l&31, kgroup = l>>5) -> 16B contiguous global per lane.
  const int grow = lane & 31;
  const int gcol = (lane >> 5) * 8;          // elements

  const unsigned short* srcAbase = Ag + (size_t)(brow + w * 32 + grow) * K_DIM + gcol;
  const unsigned short* srcBbase = Bg + (size_t)(bcol + w * 32 + grow) * K_DIM + gcol;

  // A k-subtile j of buf at [buf*65536 + w*4096 + j*1024]; B at +32768.
  auto stageA4 = [&](int buf, int kt) {      // 4 gll (k-subtiles 0..3)
#pragma unroll
    for (int j = 0; j < 4; ++j)
      __builtin_amdgcn_global_load_lds(AS1(srcAbase + (size_t)kt * 64 + j * 16),
          AS3(LDSc + buf * 65536 + w * 4096 + j * 1024), 16, 0, 0);
  };
  auto stageB2 = [&](int buf, int kt, int j0) {  // 2 gll (k-subtiles j0, j0+1)
#pragma unroll
    for (int j = 0; j < 2; ++j)
      __builtin_amdgcn_global_load_lds(AS1(srcBbase + (size_t)kt * 64 + (j0 + j) * 16),
          AS3(LDSc + buf * 65536 + 32768 + w * 4096 + (j0 + j) * 1024), 16, 0, 0);
  };

  // fragment ds_read: linear per-lane offset (conflict-free)
  const int loff = lane * 16;

  f32x16 acc[4][2] = {};
  bf16x8 a[2][4], b[2][2];   // one kk-half live at a time (j = kk&1)

  auto read_half = [&](int buf, int half) {  // 12 x ds_read_b128, all linear
#pragma unroll
    for (int j = 0; j < 2; ++j)
#pragma unroll
      for (int mi = 0; mi < 4; ++mi)
        a[j][mi] = *(const bf16x8*)(LDSc + buf * 65536 +
            (wr * 4 + mi) * 4096 + (half * 2 + j) * 1024 + loff);
#pragma unroll
    for (int j = 0; j < 2; ++j)
#pragma unroll
      for (int ni = 0; ni < 2; ++ni)
        b[j][ni] = *(const bf16x8*)(LDSc + buf * 65536 + 32768 +
            (wc * 2 + ni) * 4096 + (half * 2 + j) * 1024 + loff);
  };
  auto mma_half = [&]() {                    // 16 x mfma_32x32x16
#pragma unroll
    for (int mi = 0; mi < 4; ++mi)
#pragma unroll
      for (int ni = 0; ni < 2; ++ni)
#pragma unroll
        for (int j = 0; j < 2; ++j)
          acc[mi][ni] = __builtin_amdgcn_mfma_f32_32x32x16_bf16(
              a[j][mi], b[j][ni], acc[mi][ni], 0, 0, 0);
  };

  // one tile = 2 phases; g2: tile t+2 exists; gr: tile t+1 exists
  auto tile_body = [&](int t, int buf, bool g2, bool gr) {
    const int nxbuf = buf ^ 1;
    // Phase A
    if (g2) stageB2(buf, t + 2, 0);
    __builtin_amdgcn_s_setprio(1); mma_half(); __builtin_amdgcn_s_setprio(0);
    read_half(buf, 1);                       // kk23(t); WAR after kk01's last use
    if (g2) { VMCNT2(); } else { VMCNT0(); } // publishes all of tile t+1
    BAR();                                   // mid
    // Phase B
    if (g2) { stageB2(buf, t + 2, 2); stageA4(buf, t + 2); }
    __builtin_amdgcn_s_setprio(1); mma_half(); __builtin_amdgcn_s_setprio(0);
    if (gr) read_half(nxbuf, 0);             // kk01(t+1)
    BAR();                                   // end
  };

  // prologue: tile0 -> buf0 (8 gll), tile1 -> buf1 (8 gll); drain t0; pre-read
  stageB2(0, 0, 0); stageB2(0, 0, 2); stageA4(0, 0);
  stageB2(1, 1, 0); stageB2(1, 1, 2); stageA4(1, 1);
  VMCNT8();
  BAR();
  read_half(0, 0);

  // main loop: 32 pairs of tiles (NT = 64)
#pragma unroll 1
  for (int i = 0; i < 32; ++i) {
    const bool more = (i < 31);
    tile_body(2 * i,     0, more, true);
    tile_body(2 * i + 1, 1, more, more);
  }

  // epilogue: col = lane&31, row = (reg&3) + 8*(reg>>2) + 4*(lane>>5)
  const int c32 = lane & 31;
  const int r4 = (lane >> 5) * 4;
#pragma unroll
  for (int ni = 0; ni < 2; ++ni) {
    const int col = bcol + wc * 64 + ni * 32 + c32;
    const float bb = bias[col];
#pragma unroll
    for (int mi = 0; mi < 4; ++mi) {
      const int rowbase = brow + wr * 128 + mi * 32 + r4;
      f32x16 v = acc[mi][ni];
#pragma unroll
      for (int reg = 0; reg < 16; ++reg) {
        const int row = rowbase + (reg & 3) + 8 * (reg >> 2);
        out[(size_t)row * N_DIM + col] = v[reg] + bb;
      }
    }
  }
}

// ---------------------------------------------------------------------------
extern "C" void kernel_launch(void* const* d_in, const int* in_sizes, int n_in,
                              void* d_out, int out_size, void* d_ws, size_t ws_size,
                              hipStream_t stream) {
  const float* x    = (const float*)d_in[0];
  const float* W    = (const float*)d_in[1];
  const float* bias = (const float*)d_in[2];
  const float* lA   = (const float*)d_in[3];
  const float* lB   = (const float*)d_in[4];
  float* out = (float*)d_out;

  unsigned short* xb  = (unsigned short*)d_ws;            // 64 MiB
  unsigned short* awb = xb + (size_t)M_DIM * K_DIM;       // 32 MiB

  prep_kernel<<<1024 + CVT_BLOCKS, 256, 0, stream>>>(x, W, lA, lB, xb, awb);
  gemm_kernel<<<(M_DIM / 256) * (N_DIM / 256), 512, 0, stream>>>(xb, awb, bias, out);
}